// Round 2
// baseline (221.812 us; speedup 1.0000x reference)
//
#include <hip/hip_runtime.h>

typedef __attribute__((ext_vector_type(8))) short short8;
typedef __attribute__((ext_vector_type(4))) float floatx4;

#define B_SZ   32
#define L_IN   8192
#define C_INCH 64
#define KW     3
#define F_OUT  128
#define L_OUT  (L_IN - KW + 1)   // 8190
#define KDIM   (KW * C_INCH)     // 192

#define TILE_L  64
#define AROWS   (TILE_L + 2)     // 66
#define ASTRIDE 72               // 64 + 8 pad; rows 16B-aligned, conflict-free b128 pattern

__device__ __forceinline__ short f2bf(float f) {
    // round-to-nearest-even fp32 -> bf16 (inputs finite; no NaN path needed)
    unsigned u = __builtin_bit_cast(unsigned, f);
    unsigned r = (u + 0x7fffu + ((u >> 16) & 1u)) >> 16;
    return (short)r;
}

// One kernel, no workspace. Implicit GEMM: M = B*8190 (rows of x windows,
// each row is 192 contiguous floats at stride 64), N = 128, K = 192.
// Per block: TILE_L=64 output rows, all 128 filters. 4 waves; wave h owns
// filters [32h, 32h+32) and holds its 12 B-fragments in registers the whole
// kernel. A-tile staged fp32->bf16 in 9.5 KB LDS.
__global__ __launch_bounds__(256, 3) void conv1d_mfma(const float* __restrict__ x,
                                                      const float* __restrict__ w,
                                                      const float* __restrict__ bias,
                                                      float* __restrict__ out) {
    __shared__ short a_lds[AROWS * ASTRIDE];  // 9504 B

    const int tid  = threadIdx.x;
    const int b    = blockIdx.y;
    const int l0   = blockIdx.x * TILE_L;
    const int lane = tid & 63;
    const int wave = tid >> 6;
    const int q    = lane >> 4;   // quad 0..3
    const int nl   = lane & 15;

    // ---- B fragments: global fp32 -> bf16 registers, once per block ----
    // Validated layout (R1 passed pre-timing): lane(nl,q) of n-tile n holds
    // B[k = s*32 + q*8 + j][f = n*16 + nl], j = 0..7.  w[k*128 + f] fp32.
    short8 bfrag[6][2];
#pragma unroll
    for (int n = 0; n < 2; ++n) {
        const int f = (wave * 2 + n) * 16 + nl;
        const float* __restrict__ wf = w + f;
#pragma unroll
        for (int s = 0; s < 6; ++s) {
            float t[8];
#pragma unroll
            for (int j = 0; j < 8; ++j)
                t[j] = wf[(s * 32 + q * 8 + j) * F_OUT];
            short8 h;
#pragma unroll
            for (int j = 0; j < 8; ++j) h[j] = f2bf(t[j]);
            bfrag[s][n] = h;
        }
    }

    // ---- stage x tile: 66 rows x 64 ch, fp32 -> bf16 (528 8-elem chunks) ----
#pragma unroll
    for (int i = 0; i < 3; ++i) {
        int c = tid + 256 * i;
        if (c < AROWS * 8) {
            int p   = c >> 3;          // local row 0..65
            int col = (c & 7) * 8;     // channel 0,8,..,56
            int gl  = l0 + p;
            float4 v0, v1;
            if (gl < L_IN) {
                const float4* xp =
                    (const float4*)(x + ((size_t)b * L_IN + gl) * C_INCH + col);
                v0 = xp[0];
                v1 = xp[1];
            } else {
                v0 = make_float4(0.f, 0.f, 0.f, 0.f);
                v1 = v0;
            }
            short8 h;
            h[0] = f2bf(v0.x); h[1] = f2bf(v0.y); h[2] = f2bf(v0.z); h[3] = f2bf(v0.w);
            h[4] = f2bf(v1.x); h[5] = f2bf(v1.y); h[6] = f2bf(v1.z); h[7] = f2bf(v1.w);
            *(short8*)&a_lds[p * ASTRIDE + col] = h;
        }
    }

    __syncthreads();

    // ---- K-loop: 6 steps of 32; 4 m-tiles x 2 n-tiles per wave ----
    floatx4 acc[4][2];
#pragma unroll
    for (int m = 0; m < 4; ++m)
#pragma unroll
        for (int n = 0; n < 2; ++n) acc[m][n] = (floatx4){0.f, 0.f, 0.f, 0.f};

#pragma unroll
    for (int s = 0; s < 6; ++s) {
        short8 af[4];
#pragma unroll
        for (int m = 0; m < 4; ++m)
            af[m] = *(const short8*)&a_lds[(m * 16 + nl + (s >> 1)) * ASTRIDE
                                           + (s & 1) * 32 + q * 8];
#pragma unroll
        for (int m = 0; m < 4; ++m)
#pragma unroll
            for (int n = 0; n < 2; ++n)
                acc[m][n] = __builtin_amdgcn_mfma_f32_16x16x32_bf16(
                    af[m], bfrag[s][n], acc[m][n], 0, 0, 0);
    }

    // ---- epilogue: C/D layout col(=f within tile)=nl, row = q*4 + r ----
#pragma unroll
    for (int n = 0; n < 2; ++n) {
        const int f  = (wave * 2 + n) * 16 + nl;
        const float bv = bias[f];
#pragma unroll
        for (int m = 0; m < 4; ++m) {
            const int lb = l0 + m * 16 + q * 4;
#pragma unroll
            for (int r = 0; r < 4; ++r) {
                int l = lb + r;
                if (l < L_OUT) {
                    float v = acc[m][n][r] + bv;
                    out[((size_t)b * L_OUT + l) * F_OUT + f] = v > 0.f ? v : 0.f;
                }
            }
        }
    }
}

extern "C" void kernel_launch(void* const* d_in, const int* in_sizes, int n_in,
                              void* d_out, int out_size, void* d_ws, size_t ws_size,
                              hipStream_t stream) {
    const float* x    = (const float*)d_in[0];
    const float* w    = (const float*)d_in[1];
    const float* bias = (const float*)d_in[2];
    float* out        = (float*)d_out;
    (void)d_ws; (void)ws_size;

    conv1d_mfma<<<dim3(L_IN / TILE_L, B_SZ), 256, 0, stream>>>(x, w, bias, out);
}

// Round 3
// 219.460 us; speedup vs baseline: 1.0107x; 1.0107x over previous
//
#include <hip/hip_runtime.h>

typedef __attribute__((ext_vector_type(8))) short short8;
typedef __attribute__((ext_vector_type(4))) float floatx4;

#define B_SZ   32
#define L_IN   8192
#define C_INCH 64
#define KW     3
#define F_OUT  128
#define L_OUT  (L_IN - KW + 1)   // 8190
#define KDIM   (KW * C_INCH)     // 192

#define TILE_L  128
#define AROWS   (TILE_L + 2)     // 130
#define ASTRIDE 72               // 64 + 8 pad; rows 16B-aligned, 2-way-max (free) b128 pattern

__device__ __forceinline__ short f2bf(float f) {
    // round-to-nearest-even fp32 -> bf16 (inputs finite; no NaN path needed)
    unsigned u = __builtin_bit_cast(unsigned, f);
    unsigned r = (u + 0x7fffu + ((u >> 16) & 1u)) >> 16;
    return (short)r;
}

// Single kernel, no workspace. Implicit GEMM: M = B*8190 (each A-row is the
// 192 contiguous floats x[b, l:l+3, :]), N = 128, K = 192 (fully resident).
// Per block: TILE_L=128 output rows x all 128 filters. 4 waves; wave h owns
// filters [32h, 32h+32) and keeps its 12 B-fragments in registers for the
// whole block (w converted fp32->bf16 inline; ~200 MB total L2/L3 w traffic
// at 2048 blocks — this is the knob R3 turns, was 400 MB at TILE_L=64).
__global__ __launch_bounds__(256, 3) void conv1d_mfma(const float* __restrict__ x,
                                                      const float* __restrict__ w,
                                                      const float* __restrict__ bias,
                                                      float* __restrict__ out) {
    __shared__ short a_lds[AROWS * ASTRIDE];  // 18,720 B

    const int tid  = threadIdx.x;
    const int b    = blockIdx.y;
    const int l0   = blockIdx.x * TILE_L;
    const int lane = tid & 63;
    const int wave = tid >> 6;
    const int q    = lane >> 4;   // quad 0..3
    const int nl   = lane & 15;

    // ---- B fragments: global fp32 -> bf16 registers, once per block ----
    // Verified layout (R2 passed): lane(nl,q) of n-tile n holds
    // B[k = s*32 + q*8 + j][f = ntile*16 + nl], j = 0..7.  w[k*128 + f] fp32.
    short8 bfrag[6][2];
#pragma unroll
    for (int n = 0; n < 2; ++n) {
        const int f = (wave * 2 + n) * 16 + nl;
        const float* __restrict__ wf = w + f;
#pragma unroll
        for (int s = 0; s < 6; ++s) {
            float t[8];
#pragma unroll
            for (int j = 0; j < 8; ++j)
                t[j] = wf[(s * 32 + q * 8 + j) * F_OUT];
            short8 h;
#pragma unroll
            for (int j = 0; j < 8; ++j) h[j] = f2bf(t[j]);
            bfrag[s][n] = h;
        }
    }

    // ---- stage x tile: 130 rows x 64 ch, fp32 -> bf16 (1040 8-elem chunks) ----
#pragma unroll
    for (int i = 0; i < 5; ++i) {
        int c = tid + 256 * i;
        if (c < AROWS * 8) {
            int p   = c >> 3;          // local row 0..129
            int col = (c & 7) * 8;     // channel 0,8,..,56
            int gl  = l0 + p;
            float4 v0, v1;
            if (gl < L_IN) {
                const float4* xp =
                    (const float4*)(x + ((size_t)b * L_IN + gl) * C_INCH + col);
                v0 = xp[0];
                v1 = xp[1];
            } else {
                v0 = make_float4(0.f, 0.f, 0.f, 0.f);
                v1 = v0;
            }
            short8 h;
            h[0] = f2bf(v0.x); h[1] = f2bf(v0.y); h[2] = f2bf(v0.z); h[3] = f2bf(v0.w);
            h[4] = f2bf(v1.x); h[5] = f2bf(v1.y); h[6] = f2bf(v1.z); h[7] = f2bf(v1.w);
            *(short8*)&a_lds[p * ASTRIDE + col] = h;
        }
    }

    __syncthreads();

    // ---- K-loop: 6 steps of 32; 8 m-tiles x 2 n-tiles per wave ----
    floatx4 acc[8][2];
#pragma unroll
    for (int m = 0; m < 8; ++m)
#pragma unroll
        for (int n = 0; n < 2; ++n) acc[m][n] = (floatx4){0.f, 0.f, 0.f, 0.f};

#pragma unroll
    for (int s = 0; s < 6; ++s) {
#pragma unroll
        for (int m = 0; m < 8; ++m) {
            short8 af = *(const short8*)&a_lds[(m * 16 + nl + (s >> 1)) * ASTRIDE
                                               + (s & 1) * 32 + q * 8];
#pragma unroll
            for (int n = 0; n < 2; ++n)
                acc[m][n] = __builtin_amdgcn_mfma_f32_16x16x32_bf16(
                    af, bfrag[s][n], acc[m][n], 0, 0, 0);
        }
    }

    // ---- epilogue: C/D layout col(=f within tile)=nl, row = q*4 + r ----
#pragma unroll
    for (int n = 0; n < 2; ++n) {
        const int f  = (wave * 2 + n) * 16 + nl;
        const float bv = bias[f];
#pragma unroll
        for (int m = 0; m < 8; ++m) {
            const int lb = l0 + m * 16 + q * 4;
#pragma unroll
            for (int r = 0; r < 4; ++r) {
                int l = lb + r;
                if (l < L_OUT) {
                    float v = acc[m][n][r] + bv;
                    out[((size_t)b * L_OUT + l) * F_OUT + f] = v > 0.f ? v : 0.f;
                }
            }
        }
    }
}

extern "C" void kernel_launch(void* const* d_in, const int* in_sizes, int n_in,
                              void* d_out, int out_size, void* d_ws, size_t ws_size,
                              hipStream_t stream) {
    const float* x    = (const float*)d_in[0];
    const float* w    = (const float*)d_in[1];
    const float* bias = (const float*)d_in[2];
    float* out        = (float*)d_out;
    (void)d_ws; (void)ws_size;

    conv1d_mfma<<<dim3(L_IN / TILE_L, B_SZ), 256, 0, stream>>>(x, w, bias, out);
}